// Round 6
// baseline (611.294 us; speedup 1.0000x reference)
//
#include <hip/hip_runtime.h>

#define N_ROWS   131072
#define D_IN     512
#define D_H      128
#define K_CODES  256
#define NT       512          // 8 waves, 16 rows each
#define PNT      256          // prep/finalize block size (layout-coupled, keep 256)
#define RPB      128          // rows per block
#define NBLK     (N_ROWS / RPB)
#define SA       136          // s_A row stride in bf16 elems (272 B, breaks power-of-2)
#define NROUND   28           // 28 x 16KB B rounds = whole wsb, consumed linearly

typedef __attribute__((ext_vector_type(8))) short bf16x8;
typedef __attribute__((ext_vector_type(4))) float f32x4;

__device__ inline unsigned short f2bf(float f) {
    unsigned u = __float_as_uint(f);
    return (unsigned short)((u + 0x7FFFu + ((u >> 16) & 1u)) >> 16);
}
__device__ inline ushort4 f2bf4(float4 v) {
    return make_ushort4(f2bf(v.x), f2bf(v.y), f2bf(v.z), f2bf(v.w));
}
__device__ inline bf16x8 f2bf8(float4 a, float4 b) {
    bf16x8 r;
    r[0] = (short)f2bf(a.x); r[1] = (short)f2bf(a.y); r[2] = (short)f2bf(a.z); r[3] = (short)f2bf(a.w);
    r[4] = (short)f2bf(b.x); r[5] = (short)f2bf(b.y); r[6] = (short)f2bf(b.z); r[7] = (short)f2bf(b.w);
    return r;
}

// async global->LDS DMA, 16B per lane; LDS dest is wave-uniform base + lane*16
typedef const __attribute__((address_space(1))) void* gv_t;
typedef __attribute__((address_space(3))) void* lv_t;
__device__ __forceinline__ void gll16(const unsigned short* g, unsigned short* l) {
    __builtin_amdgcn_global_load_lds((gv_t)g, (lv_t)l, 16, 0, 0);
}

// ---------------- prep: reorder weights/codebooks into MFMA B-fragment order ----------------
// B-fragment order: frag(ct,ks) is 64 lanes x 8 bf16, lane = qd*16+nn holds
// B[n = ct*16+nn][k = ks*32 + qd*8 + j], j=0..7.  One 32KB "round" = 8 ct x 4 ks.
// wsb layout (ushorts): [0..65535] Wenc rounds kc=0..3 | [65536..163839] cb (t,half) rounds | [163840..229375] Wdec rounds c=0..3
__global__ void rqvae_prep(const float* __restrict__ Wenc,
                           const float* __restrict__ Wdec,
                           const float* __restrict__ cb0,
                           const float* __restrict__ cb1,
                           const float* __restrict__ cb2,
                           unsigned short* __restrict__ wsb,
                           float* __restrict__ norms)
{
    const int tid = threadIdx.x;
    const int b = blockIdx.x;
    const float* cbs[3] = {cb0, cb1, cb2};
    if (b < 112) {
        const int g = b * 256 + tid;            // ushort8 group id, 0..28671
        const int lane = g & 63, ks = (g >> 6) & 3, ct = (g >> 8) & 7;
        const int nn = lane & 15, qd = lane >> 4;
        const float* src;
        if (g < 8192) {                         // Wenc: kc = g>>11
            const int kc = g >> 11;
            src = Wenc + (ct * 16 + nn) * D_IN + kc * 128 + ks * 32 + qd * 8;
        } else if (g < 20480) {                 // cb: t = (g-8192)>>12, half = bit 11
            const int r = g - 8192;
            const int t = r >> 12, half = (r >> 11) & 1;
            src = cbs[t] + (long)(half * 128 + ct * 16 + nn) * D_H + ks * 32 + qd * 8;
        } else {                                // Wdec: c = (g-20480)>>11
            const int r = g - 20480;
            const int c = r >> 11;
            src = Wdec + (long)(c * 128 + ct * 16 + nn) * D_H + ks * 32 + qd * 8;
        }
        float4 v0 = *(const float4*)(src);
        float4 v1 = *(const float4*)(src + 4);
        *(ushort4*)(wsb + (long)g * 8)     = f2bf4(v0);
        *(ushort4*)(wsb + (long)g * 8 + 4) = f2bf4(v1);
    } else {
        const int t = b - 112;                  // norm blocks: one code per thread
        const float4* r = (const float4*)(cbs[t] + (long)tid * D_H);
        float s = 0.f;
        #pragma unroll
        for (int d = 0; d < 32; ++d) { float4 v = r[d]; s += v.x*v.x + v.y*v.y + v.z*v.z + v.w*v.w; }
        norms[t * K_CODES + tid] = -0.5f * s;
    }
}

// ---------------- main ----------------
// T4 counted-vmcnt pipeline: per round, STAGE(r+1) stays IN FLIGHT across both
// raw s_barriers; s_waitcnt vmcnt(2) retires only STAGE(r) (its 2 DMA loads are
// the oldest outstanding). __syncthreads (which drains vmcnt(0) and killed the
// rounds-3..5 pipelines) appears only once, at the prologue.
// vmcnt bookkeeping by issue order: phase-1 A loads precede STAGE (their f2bf
// consumption can never force vmcnt(0) past the stage pair); phase-3 emb diffs
// are prefetched one round ahead (16 loads before the wait -> vmcnt(18)/(16)).
// Phase-2 rounds have no other VMEM -> exact vmcnt(2). Only the 3 per-stage
// codebook-gather epilogues still drain deep (3 drains/block instead of 28).
__global__ __launch_bounds__(NT, 4) void rqvae_main(
    const float* __restrict__ emb,
    const float* __restrict__ cb0,
    const float* __restrict__ cb1,
    const float* __restrict__ cb2,
    const unsigned short* __restrict__ wsb,
    const float* __restrict__ norms,
    float* __restrict__ acc_rq,
    float* __restrict__ acc_recon,
    int* __restrict__ used)
{
    __shared__ unsigned short s_A[RPB * SA];   // 34816 B: latent/rem/restored, wave-private rows
    __shared__ unsigned short s_B[2][8192];    // 32768 B: double-buffered 16KB B rounds
    __shared__ float s_cn[3 * K_CODES];        // 3072 B  -> total 70656 B, 2 blocks/CU

    const int tid  = threadIdx.x;
    const int wv   = tid >> 6;                 // 0..7
    const int lane = tid & 63;
    const int nn   = lane & 15;
    const int qd   = lane >> 4;
    const int wrow = wv * 16;                  // this wave's 16 rows in the block
    const long blkRow = (long)blockIdx.x * RPB;

    for (int i = tid; i < 3 * K_CODES; i += NT) s_cn[i] = norms[i];

#define STAGE(r, buf) do {                                                      \
        const unsigned short* _s = wsb + (r) * 8192;                            \
        _Pragma("unroll")                                                       \
        for (int _i = 0; _i < 2; ++_i)                                          \
            gll16(_s + _i * 4096 + wv * 512 + lane * 8,                         \
                  &s_B[buf][_i * 4096 + wv * 512]);                             \
    } while (0)
// counted wait; sched_barrier pins code motion across the asm (rule #18)
#define VMCNT(n) do {                                                           \
        asm volatile("s_waitcnt vmcnt(" #n ")" ::: "memory");                   \
        __builtin_amdgcn_sched_barrier(0);                                      \
    } while (0)
// raw barrier, pinned both sides; NO vmcnt drain
#define SBAR() do {                                                             \
        __builtin_amdgcn_sched_barrier(0);                                      \
        __builtin_amdgcn_s_barrier();                                           \
        __builtin_amdgcn_sched_barrier(0);                                      \
    } while (0)

    STAGE(0, 0);
    __syncthreads();                           // only full drain: round-0 data + s_cn visible
    int cur = 0;

    f32x4 rem[8];
    #pragma unroll
    for (int ct = 0; ct < 8; ++ct) rem[ct] = {0.f,0.f,0.f,0.f};

    // ---- Phase 1: latent = emb @ Wenc^T; rounds 0..7, A direct global->reg ----
    #pragma unroll 1
    for (int kc = 0; kc < 4; ++kc) {
        // A loads issued BEFORE the stage pair so their consumption waits
        // vmcnt(2), never vmcnt(0)
        float4 t0[4], t1[4];
        {
            const float* arow = emb + (blkRow + wrow + nn) * D_IN + kc * 128 + qd * 8;
            #pragma unroll
            for (int ks = 0; ks < 4; ++ks) {
                t0[ks] = *(const float4*)(arow + ks * 32);
                t1[ks] = *(const float4*)(arow + ks * 32 + 4);
            }
        }
        STAGE(kc * 2 + 1, cur ^ 1);
        __builtin_amdgcn_sched_barrier(0);
        bf16x8 af[4];
        #pragma unroll
        for (int ks = 0; ks < 4; ++ks) af[ks] = f2bf8(t0[ks], t1[ks]);
        VMCNT(2);                              // STAGE(2kc) retired (oldest); stage pair in flight
        SBAR();
        __builtin_amdgcn_s_setprio(1);
        #pragma unroll
        for (int ctc = 0; ctc < 4; ++ctc)
            #pragma unroll
            for (int ks = 0; ks < 4; ++ks) {
                bf16x8 bf = *(const bf16x8*)&s_B[cur][(ctc * 4 + ks) * 512 + lane * 8];
                rem[ctc] = __builtin_amdgcn_mfma_f32_16x16x32_bf16(af[ks], bf, rem[ctc], 0, 0, 0);
            }
        __builtin_amdgcn_s_setprio(0);
        SBAR();                                // release cur
        cur ^= 1;

        STAGE(kc * 2 + 2, cur ^ 1);            // kc=3 stages round 8 = first phase-2 round
        VMCNT(2);
        SBAR();
        __builtin_amdgcn_s_setprio(1);
        #pragma unroll
        for (int ctc = 0; ctc < 4; ++ctc)
            #pragma unroll
            for (int ks = 0; ks < 4; ++ks) {
                bf16x8 bf = *(const bf16x8*)&s_B[cur][(ctc * 4 + ks) * 512 + lane * 8];
                rem[4 + ctc] = __builtin_amdgcn_mfma_f32_16x16x32_bf16(af[ks], bf, rem[4 + ctc], 0, 0, 0);
            }
        __builtin_amdgcn_s_setprio(0);
        SBAR();
        cur ^= 1;
    }

    // latent -> s_A bf16 (wave-private rows; no barrier needed)
    #pragma unroll
    for (int ct = 0; ct < 8; ++ct)
        #pragma unroll
        for (int e = 0; e < 4; ++e)
            s_A[(wrow + qd * 4 + e) * SA + ct * 16 + nn] = f2bf(rem[ct][e]);

    // ---- Phase 2: three RQ stages; rounds 8..19 (4 x 16KB per stage) ----
    float local_rq = 0.f;
    int bis0[4], bis1[4], bis2[4];             // winning codes, named (no dynamic index)
    #pragma unroll 1
    for (int t = 0; t < 3; ++t) {
        const float* __restrict__ cb = (t == 0) ? cb0 : ((t == 1) ? cb1 : cb2);
        float bv[4]; int bi[4];
        #pragma unroll
        for (int e = 0; e < 4; ++e) { bv[e] = -3.402823466e38f; bi[e] = 0; }

        bf16x8 af[4];
        #pragma unroll
        for (int ks = 0; ks < 4; ++ks)
            af[ks] = *(const bf16x8*)&s_A[(wrow + nn) * SA + ks * 32 + qd * 8];

        #pragma unroll 1
        for (int rl = 0; rl < 4; ++rl) {
            STAGE(9 + t * 4 + rl, cur ^ 1);    // <= round 20, always valid
            VMCNT(2);
            SBAR();
            __builtin_amdgcn_s_setprio(1);
            f32x4 sc[4];
            #pragma unroll
            for (int ctc = 0; ctc < 4; ++ctc) {
                f32x4 s0 = {0.f,0.f,0.f,0.f};
                #pragma unroll
                for (int ks = 0; ks < 4; ++ks) {
                    bf16x8 bf = *(const bf16x8*)&s_B[cur][(ctc * 4 + ks) * 512 + lane * 8];
                    s0 = __builtin_amdgcn_mfma_f32_16x16x32_bf16(af[ks], bf, s0, 0, 0, 0);
                }
                sc[ctc] = s0;
            }
            __builtin_amdgcn_s_setprio(0);
            SBAR();                            // release cur; epilogue overlaps others' staging
            #pragma unroll
            for (int ctc = 0; ctc < 4; ++ctc) {
                const int code = rl * 64 + ctc * 16 + nn;
                const float cn = s_cn[t * K_CODES + code];
                #pragma unroll
                for (int e = 0; e < 4; ++e) {
                    const float v0 = sc[ctc][e] + cn;
                    if (v0 > bv[e] || (v0 == bv[e] && code < bi[e])) { bv[e] = v0; bi[e] = code; }
                }
            }
            cur ^= 1;
        }
        // argmax over the 16 nn-lanes of each quad (tie -> lowest index)
        #pragma unroll
        for (int e = 0; e < 4; ++e) {
            float v = bv[e]; int i0 = bi[e];
            #pragma unroll
            for (int m = 8; m >= 1; m >>= 1) {
                const float ov = __shfl_xor(v, m);
                const int   oi = __shfl_xor(i0, m);
                if (ov > v || (ov == v && oi < i0)) { v = ov; i0 = oi; }
            }
            bi[e] = i0;
            if (t == 0) bis0[e] = i0; else if (t == 1) bis1[e] = i0; else bis2[e] = i0;
            if (nn == 0) used[t * K_CODES + i0] = 1;
        }
        // update rem with fp32 codebook rows (gathers drain the pipe; 3x per block only)
        #pragma unroll
        for (int ct = 0; ct < 8; ++ct)
            #pragma unroll
            for (int e = 0; e < 4; ++e) {
                const float c = cb[(long)bi[e] * D_H + ct * 16 + nn];
                const float rr = rem[ct][e] - c;
                rem[ct][e] = rr;
                local_rq += rr * rr;
                if (t < 2)
                    s_A[(wrow + qd * 4 + e) * SA + ct * 16 + nn] = f2bf(rr);
            }
    }

    // restored = cb0[i0]+cb1[i1]+cb2[i2] re-gathered (same add order as res += c) -> s_A bf16
    #pragma unroll
    for (int ct = 0; ct < 8; ++ct)
        #pragma unroll
        for (int e = 0; e < 4; ++e) {
            const int co = ct * 16 + nn;
            const float r = cb0[(long)bis0[e] * D_H + co]
                          + cb1[(long)bis1[e] * D_H + co]
                          + cb2[(long)bis2[e] * D_H + co];
            s_A[(wrow + qd * 4 + e) * SA + co] = f2bf(r);
        }

    // ---- Phase 3: recon = restored @ Wdec^T; rounds 20..27, diff vs fp32 emb ----
    float local_rec = 0.f;
    {
        bf16x8 af[4];
        #pragma unroll
        for (int ks = 0; ks < 4; ++ks)
            af[ks] = *(const bf16x8*)&s_A[(wrow + nn) * SA + ks * 32 + qd * 8];
        // prefetch emb diff values for rl=0 (16 scalar loads, one round ahead pattern)
        float ep[4][4];
        #pragma unroll
        for (int ctc = 0; ctc < 4; ++ctc)
            #pragma unroll
            for (int e = 0; e < 4; ++e)
                ep[ctc][e] = emb[(blkRow + wrow + qd * 4 + e) * D_IN + ctc * 16 + nn];
        #pragma unroll 1
        for (int rl = 0; rl < 8; ++rl) {
            float ep2[4][4];
            if (rl < 7) {
                STAGE(21 + rl, cur ^ 1);
                #pragma unroll
                for (int ctc = 0; ctc < 4; ++ctc)
                    #pragma unroll
                    for (int e = 0; e < 4; ++e)
                        ep2[ctc][e] = emb[(blkRow + wrow + qd * 4 + e) * D_IN + (rl + 1) * 64 + ctc * 16 + nn];
                VMCNT(18);                     // retires STAGE(20+rl)+old ep; keeps stage pair + 16 ep2
            } else {
                VMCNT(16);                     // last round: retires STAGE(27); keeps 16 ep (already old)
            }
            SBAR();
            __builtin_amdgcn_s_setprio(1);
            f32x4 rr[4];
            #pragma unroll
            for (int ctc = 0; ctc < 4; ++ctc) {
                f32x4 r0 = {0.f,0.f,0.f,0.f};
                #pragma unroll
                for (int ks = 0; ks < 4; ++ks) {
                    bf16x8 bf = *(const bf16x8*)&s_B[cur][(ctc * 4 + ks) * 512 + lane * 8];
                    r0 = __builtin_amdgcn_mfma_f32_16x16x32_bf16(af[ks], bf, r0, 0, 0, 0);
                }
                rr[ctc] = r0;
            }
            __builtin_amdgcn_s_setprio(0);
            SBAR();                            // release cur; diff epilogue overlaps staging
            #pragma unroll
            for (int ctc = 0; ctc < 4; ++ctc)
                #pragma unroll
                for (int e = 0; e < 4; ++e) {
                    const float d0 = rr[ctc][e] - ep[ctc][e];
                    local_rec += d0 * d0;
                }
            if (rl < 7) {
                #pragma unroll
                for (int ctc = 0; ctc < 4; ++ctc)
                    #pragma unroll
                    for (int e = 0; e < 4; ++e)
                        ep[ctc][e] = ep2[ctc][e];
            }
            cur ^= 1;
        }
    }
#undef STAGE
#undef VMCNT
#undef SBAR

    // ---- wave shuffle reduce, one atomic pair per wave ----
    float r1 = local_rq, r2 = local_rec;
    #pragma unroll
    for (int m = 32; m >= 1; m >>= 1) { r1 += __shfl_xor(r1, m); r2 += __shfl_xor(r2, m); }
    if (lane == 0) { atomicAdd(acc_rq, r1); atomicAdd(acc_recon, r2); }
}

__global__ void rqvae_finalize(const float* __restrict__ acc,
                               const int* __restrict__ used,
                               float* __restrict__ out)
{
    __shared__ int s_sum[4];
    const int tid = threadIdx.x;
    for (int t = 0; t < 3; ++t) {
        int v = (used[t * K_CODES + tid] != 0) ? 1 : 0;
        #pragma unroll
        for (int off = 32; off >= 1; off >>= 1) v += __shfl_down(v, off);
        if ((tid & 63) == 0) s_sum[tid >> 6] = v;
        __syncthreads();
        if (tid == 0) out[3 + t] = (float)(s_sum[0] + s_sum[1] + s_sum[2] + s_sum[3]);
        __syncthreads();
    }
    if (tid == 0) {
        const float rq    = 1.25f * acc[0] / ((float)N_ROWS * 128.0f);
        const float recon =         acc[1] / ((float)N_ROWS * 512.0f);
        out[0] = recon + rq;
        out[1] = recon;
        out[2] = rq;
    }
}

extern "C" void kernel_launch(void* const* d_in, const int* in_sizes, int n_in,
                              void* d_out, int out_size, void* d_ws, size_t ws_size,
                              hipStream_t stream) {
    const float* emb  = (const float*)d_in[0];
    const float* Wenc = (const float*)d_in[1];
    const float* Wdec = (const float*)d_in[2];
    const float* cb0  = (const float*)d_in[3];
    const float* cb1  = (const float*)d_in[4];
    const float* cb2  = (const float*)d_in[5];

    // workspace layout (bytes): [0] 2 f32 acc | [64] 768 int used | [3200] 768 f32 norms | [8192] 448KB bf16 frags
    float* ws_f  = (float*)d_ws;
    int*   used  = (int*)((char*)d_ws + 64);
    float* norms = (float*)((char*)d_ws + 3200);
    unsigned short* wsb = (unsigned short*)((char*)d_ws + 8192);

    hipMemsetAsync(d_ws, 0, 3200, stream);
    rqvae_prep<<<115, PNT, 0, stream>>>(Wenc, Wdec, cb0, cb1, cb2, wsb, norms);
    rqvae_main<<<NBLK, NT, 0, stream>>>(emb, cb0, cb1, cb2, wsb, norms,
                                        ws_f + 0, ws_f + 1, used);
    rqvae_finalize<<<1, PNT, 0, stream>>>(ws_f, used, (float*)d_out);
}

// Round 7
// 544.017 us; speedup vs baseline: 1.1237x; 1.1237x over previous
//
#include <hip/hip_runtime.h>

#define N_ROWS   131072
#define D_IN     512
#define D_H      128
#define K_CODES  256
#define NT       256          // 4 waves
#define RPB      128          // rows per block: 32 per wave (2 x 16-row MFMA tiles)
#define NBLK     (N_ROWS / RPB)
#define SA       136          // s_A row stride in bf16 elems (272 B, breaks power-of-2)

typedef __attribute__((ext_vector_type(8))) short bf16x8;
typedef __attribute__((ext_vector_type(4))) float f32x4;

__device__ inline unsigned short f2bf(float f) {
    unsigned u = __float_as_uint(f);
    return (unsigned short)((u + 0x7FFFu + ((u >> 16) & 1u)) >> 16);
}
__device__ inline ushort4 f2bf4(float4 v) {
    return make_ushort4(f2bf(v.x), f2bf(v.y), f2bf(v.z), f2bf(v.w));
}

// ---------------- prep: reorder weights/codebooks into MFMA B-fragment order ----------------
// B-fragment order: frag(ct,ks) is 64 lanes x 8 bf16, lane = qd*16+nn holds
// B[n = ct*16+nn][k = ks*32 + qd*8 + j], j=0..7.  One 32KB "round" = 8 ct x 4 ks.
// wsb layout (ushorts): [0..65535] Wenc rounds kc=0..3 | [65536..163839] cb (t,half) rounds | [163840..229375] Wdec rounds c=0..3
__global__ void rqvae_prep(const float* __restrict__ Wenc,
                           const float* __restrict__ Wdec,
                           const float* __restrict__ cb0,
                           const float* __restrict__ cb1,
                           const float* __restrict__ cb2,
                           unsigned short* __restrict__ wsb,
                           float* __restrict__ norms)
{
    const int tid = threadIdx.x;
    const int b = blockIdx.x;
    const float* cbs[3] = {cb0, cb1, cb2};
    if (b < 112) {
        const int g = b * 256 + tid;            // ushort8 group id, 0..28671
        const int lane = g & 63, ks = (g >> 6) & 3, ct = (g >> 8) & 7;
        const int nn = lane & 15, qd = lane >> 4;
        const float* src;
        if (g < 8192) {                         // Wenc: kc = g>>11
            const int kc = g >> 11;
            src = Wenc + (ct * 16 + nn) * D_IN + kc * 128 + ks * 32 + qd * 8;
        } else if (g < 20480) {                 // cb: t = (g-8192)>>12, half = bit 11
            const int r = g - 8192;
            const int t = r >> 12, half = (r >> 11) & 1;
            src = cbs[t] + (long)(half * 128 + ct * 16 + nn) * D_H + ks * 32 + qd * 8;
        } else {                                // Wdec: c = (g-20480)>>11
            const int r = g - 20480;
            const int c = r >> 11;
            src = Wdec + (long)(c * 128 + ct * 16 + nn) * D_H + ks * 32 + qd * 8;
        }
        float4 v0 = *(const float4*)(src);
        float4 v1 = *(const float4*)(src + 4);
        *(ushort4*)(wsb + (long)g * 8)     = f2bf4(v0);
        *(ushort4*)(wsb + (long)g * 8 + 4) = f2bf4(v1);
    } else {
        const int t = b - 112;                  // norm blocks: one code per thread
        const float4* r = (const float4*)(cbs[t] + (long)tid * D_H);
        float s = 0.f;
        #pragma unroll
        for (int d = 0; d < 32; ++d) { float4 v = r[d]; s += v.x*v.x + v.y*v.y + v.z*v.z + v.w*v.w; }
        norms[t * K_CODES + tid] = -0.5f * s;
    }
}

// ---------------- main ----------------
// Round-0 structure (best measured: 283us) + ONE change: per-block ROTATED round
// order. All 1024 blocks used to stage the same 448KB wsb in the same order in
// quasi-lockstep -> all 32 CUs of an XCD request the SAME L2 lines simultaneously
// every round (same-line multicast contention; invariant across all 6 prior
// scheduling variants, which is why none moved). Rotation rot=(blockIdx>>3)&3
// spreads co-resident same-XCD blocks (blockIdx = xcd mod 8, hence >>3) across
// 4 different 32KB regions. Legal: phase-1 K-chunks commute (MFMA accumulate),
// phase-2 halves commute exactly (argmax with explicit (v,idx) tie-break),
// phase-3 col-chunks commute (local fp32 sum).
__global__ __launch_bounds__(NT, 2) void rqvae_main(
    const float* __restrict__ emb,
    const float* __restrict__ cb0,
    const float* __restrict__ cb1,
    const float* __restrict__ cb2,
    const unsigned short* __restrict__ wsb,
    const float* __restrict__ norms,
    float* __restrict__ acc_rq,
    float* __restrict__ acc_recon,
    int* __restrict__ used)
{
    __shared__ unsigned short s_A[RPB * SA];   // 34816 B: A operand (emb chunk / rem / restored), padded
    __shared__ unsigned short s_B[16384];      // 32768 B: one B round, fragment-linear
    __shared__ float s_cn[3 * K_CODES];        // 3072 B

    const int tid  = threadIdx.x;
    const int wv   = tid >> 6;
    const int lane = tid & 63;
    const int nn   = lane & 15;
    const int qd   = lane >> 4;
    const long blkRow = (long)blockIdx.x * RPB;
    const int rot  = (blockIdx.x >> 3) & 3;    // same-XCD decorrelator
    const float* cbs[3] = {cb0, cb1, cb2};

    for (int i = tid; i < 3 * K_CODES; i += NT) s_cn[i] = norms[i];

    f32x4 rem[2][8], res[2][8];
    #pragma unroll
    for (int rt = 0; rt < 2; ++rt)
        #pragma unroll
        for (int ct = 0; ct < 8; ++ct) { rem[rt][ct] = {0.f,0.f,0.f,0.f}; res[rt][ct] = {0.f,0.f,0.f,0.f}; }

    // ---- Phase 1: latent = emb @ Wenc^T (4 rounds of K=128, rotated order) ----
    for (int kk = 0; kk < 4; ++kk) {
        const int kc = (kk + rot) & 3;
        __syncthreads();
        #pragma unroll
        for (int it = 0; it < 16; ++it) {                   // A: 128 rows x 32 float4
            const int g = tid + it * NT, row = g >> 5, c4 = g & 31;
            float4 v = *(const float4*)(emb + (blkRow + row) * D_IN + kc * 128 + c4 * 4);
            *(ushort4*)&s_A[row * SA + c4 * 4] = f2bf4(v);
        }
        {   // B: straight 32KB copy, fragment-linear
            const bf16x8* src = (const bf16x8*)(wsb + kc * 16384);
            bf16x8* dst = (bf16x8*)s_B;
            #pragma unroll
            for (int i = 0; i < 8; ++i) dst[tid + i * NT] = src[tid + i * NT];
        }
        __syncthreads();
        bf16x8 af[2][4];
        #pragma unroll
        for (int rt = 0; rt < 2; ++rt)
            #pragma unroll
            for (int ks = 0; ks < 4; ++ks)
                af[rt][ks] = *(const bf16x8*)&s_A[(wv * 32 + rt * 16 + nn) * SA + ks * 32 + qd * 8];
        #pragma unroll
        for (int ct = 0; ct < 8; ++ct)
            #pragma unroll
            for (int ks = 0; ks < 4; ++ks) {
                bf16x8 bf = *(const bf16x8*)&s_B[(ct * 4 + ks) * 512 + lane * 8];
                rem[0][ct] = __builtin_amdgcn_mfma_f32_16x16x32_bf16(af[0][ks], bf, rem[0][ct], 0, 0, 0);
                rem[1][ct] = __builtin_amdgcn_mfma_f32_16x16x32_bf16(af[1][ks], bf, rem[1][ct], 0, 0, 0);
            }
    }

    // latent -> s_A bf16 (wave-private rows)
    #pragma unroll
    for (int rt = 0; rt < 2; ++rt)
        #pragma unroll
        for (int ct = 0; ct < 8; ++ct)
            #pragma unroll
            for (int e = 0; e < 4; ++e)
                s_A[(wv * 32 + rt * 16 + qd * 4 + e) * SA + ct * 16 + nn] = f2bf(rem[rt][ct][e]);

    // ---- Phase 2: three RQ stages (halves rotated within each stage) ----
    float local_rq = 0.f;
    for (int t = 0; t < 3; ++t) {
        const float* __restrict__ cb = cbs[t];
        float bv[2][4]; int bi[2][4];
        #pragma unroll
        for (int rt = 0; rt < 2; ++rt)
            #pragma unroll
            for (int e = 0; e < 4; ++e) { bv[rt][e] = -3.402823466e38f; bi[rt][e] = 0; }

        bf16x8 af[2][4];
        #pragma unroll
        for (int rt = 0; rt < 2; ++rt)
            #pragma unroll
            for (int ks = 0; ks < 4; ++ks)
                af[rt][ks] = *(const bf16x8*)&s_A[(wv * 32 + rt * 16 + nn) * SA + ks * 32 + qd * 8];

        for (int hh = 0; hh < 2; ++hh) {
            const int half = hh ^ (rot & 1);
            __syncthreads();
            {
                const bf16x8* src = (const bf16x8*)(wsb + 65536 + (t * 2 + half) * 16384);
                bf16x8* dst = (bf16x8*)s_B;
                #pragma unroll
                for (int i = 0; i < 8; ++i) dst[tid + i * NT] = src[tid + i * NT];
            }
            __syncthreads();
            #pragma unroll
            for (int ct = 0; ct < 8; ++ct) {
                f32x4 s0 = {0.f,0.f,0.f,0.f}, s1 = {0.f,0.f,0.f,0.f};
                #pragma unroll
                for (int ks = 0; ks < 4; ++ks) {
                    bf16x8 bf = *(const bf16x8*)&s_B[(ct * 4 + ks) * 512 + lane * 8];
                    s0 = __builtin_amdgcn_mfma_f32_16x16x32_bf16(af[0][ks], bf, s0, 0, 0, 0);
                    s1 = __builtin_amdgcn_mfma_f32_16x16x32_bf16(af[1][ks], bf, s1, 0, 0, 0);
                }
                const int code = half * 128 + ct * 16 + nn;
                const float cn = s_cn[t * K_CODES + code];
                #pragma unroll
                for (int e = 0; e < 4; ++e) {
                    const float v0 = s0[e] + cn;
                    if (v0 > bv[0][e] || (v0 == bv[0][e] && code < bi[0][e])) { bv[0][e] = v0; bi[0][e] = code; }
                    const float v1 = s1[e] + cn;
                    if (v1 > bv[1][e] || (v1 == bv[1][e] && code < bi[1][e])) { bv[1][e] = v1; bi[1][e] = code; }
                }
            }
        }
        // argmax over the 16 nn-lanes of each quad (tie -> lowest index)
        #pragma unroll
        for (int rt = 0; rt < 2; ++rt)
            #pragma unroll
            for (int e = 0; e < 4; ++e) {
                float v = bv[rt][e]; int i0 = bi[rt][e];
                #pragma unroll
                for (int m = 8; m >= 1; m >>= 1) {
                    const float ov = __shfl_xor(v, m);
                    const int   oi = __shfl_xor(i0, m);
                    if (ov > v || (ov == v && oi < i0)) { v = ov; i0 = oi; }
                }
                bi[rt][e] = i0;
                if (nn == 0) used[t * K_CODES + i0] = 1;
            }
        // update rem/res with fp32 codebook rows
        #pragma unroll
        for (int rt = 0; rt < 2; ++rt)
            #pragma unroll
            for (int ct = 0; ct < 8; ++ct)
                #pragma unroll
                for (int e = 0; e < 4; ++e) {
                    const float c = cb[(long)bi[rt][e] * D_H + ct * 16 + nn];
                    const float r = rem[rt][ct][e] - c;
                    rem[rt][ct][e] = r;
                    res[rt][ct][e] += c;
                    local_rq += r * r;
                    if (t < 2)
                        s_A[(wv * 32 + rt * 16 + qd * 4 + e) * SA + ct * 16 + nn] = f2bf(r);
                }
    }

    // restored -> s_A bf16 (wave-private)
    #pragma unroll
    for (int rt = 0; rt < 2; ++rt)
        #pragma unroll
        for (int ct = 0; ct < 8; ++ct)
            #pragma unroll
            for (int e = 0; e < 4; ++e)
                s_A[(wv * 32 + rt * 16 + qd * 4 + e) * SA + ct * 16 + nn] = f2bf(res[rt][ct][e]);

    // ---- Phase 3: recon = restored @ Wdec^T (rotated col-chunk order), diff vs fp32 emb ----
    float local_rec = 0.f;
    {
        bf16x8 af[2][4];
        #pragma unroll
        for (int rt = 0; rt < 2; ++rt)
            #pragma unroll
            for (int ks = 0; ks < 4; ++ks)
                af[rt][ks] = *(const bf16x8*)&s_A[(wv * 32 + rt * 16 + nn) * SA + ks * 32 + qd * 8];
        for (int cc = 0; cc < 4; ++cc) {
            const int c = (cc + rot) & 3;
            __syncthreads();
            {
                const bf16x8* src = (const bf16x8*)(wsb + 163840 + c * 16384);
                bf16x8* dst = (bf16x8*)s_B;
                #pragma unroll
                for (int i = 0; i < 8; ++i) dst[tid + i * NT] = src[tid + i * NT];
            }
            __syncthreads();
            #pragma unroll
            for (int ct = 0; ct < 8; ++ct) {
                f32x4 r0 = {0.f,0.f,0.f,0.f}, r1 = {0.f,0.f,0.f,0.f};
                #pragma unroll
                for (int ks = 0; ks < 4; ++ks) {
                    bf16x8 bf = *(const bf16x8*)&s_B[(ct * 4 + ks) * 512 + lane * 8];
                    r0 = __builtin_amdgcn_mfma_f32_16x16x32_bf16(af[0][ks], bf, r0, 0, 0, 0);
                    r1 = __builtin_amdgcn_mfma_f32_16x16x32_bf16(af[1][ks], bf, r1, 0, 0, 0);
                }
                const int col = c * 128 + ct * 16 + nn;
                #pragma unroll
                for (int e = 0; e < 4; ++e) {
                    const float e0 = emb[(blkRow + wv * 32 +      qd * 4 + e) * D_IN + col];
                    const float e1 = emb[(blkRow + wv * 32 + 16 + qd * 4 + e) * D_IN + col];
                    const float d0 = r0[e] - e0;
                    const float d1 = r1[e] - e1;
                    local_rec += d0 * d0 + d1 * d1;
                }
            }
        }
    }

    // ---- wave shuffle reduce, one atomic pair per wave ----
    float r1 = local_rq, r2 = local_rec;
    #pragma unroll
    for (int m = 32; m >= 1; m >>= 1) { r1 += __shfl_xor(r1, m); r2 += __shfl_xor(r2, m); }
    if (lane == 0) { atomicAdd(acc_rq, r1); atomicAdd(acc_recon, r2); }
}

__global__ void rqvae_finalize(const float* __restrict__ acc,
                               const int* __restrict__ used,
                               float* __restrict__ out)
{
    __shared__ int s_sum[4];
    const int tid = threadIdx.x;
    for (int t = 0; t < 3; ++t) {
        int v = (used[t * K_CODES + tid] != 0) ? 1 : 0;
        #pragma unroll
        for (int off = 32; off >= 1; off >>= 1) v += __shfl_down(v, off);
        if ((tid & 63) == 0) s_sum[tid >> 6] = v;
        __syncthreads();
        if (tid == 0) out[3 + t] = (float)(s_sum[0] + s_sum[1] + s_sum[2] + s_sum[3]);
        __syncthreads();
    }
    if (tid == 0) {
        const float rq    = 1.25f * acc[0] / ((float)N_ROWS * 128.0f);
        const float recon =         acc[1] / ((float)N_ROWS * 512.0f);
        out[0] = recon + rq;
        out[1] = recon;
        out[2] = rq;
    }
}

extern "C" void kernel_launch(void* const* d_in, const int* in_sizes, int n_in,
                              void* d_out, int out_size, void* d_ws, size_t ws_size,
                              hipStream_t stream) {
    const float* emb  = (const float*)d_in[0];
    const float* Wenc = (const float*)d_in[1];
    const float* Wdec = (const float*)d_in[2];
    const float* cb0  = (const float*)d_in[3];
    const float* cb1  = (const float*)d_in[4];
    const float* cb2  = (const float*)d_in[5];

    // workspace layout (bytes): [0] 2 f32 acc | [64] 768 int used | [3200] 768 f32 norms | [8192] 448KB bf16 frags
    float* ws_f  = (float*)d_ws;
    int*   used  = (int*)((char*)d_ws + 64);
    float* norms = (float*)((char*)d_ws + 3200);
    unsigned short* wsb = (unsigned short*)((char*)d_ws + 8192);

    hipMemsetAsync(d_ws, 0, 3200, stream);
    rqvae_prep<<<115, NT, 0, stream>>>(Wenc, Wdec, cb0, cb1, cb2, wsb, norms);
    rqvae_main<<<NBLK, NT, 0, stream>>>(emb, cb0, cb1, cb2, wsb, norms,
                                        ws_f + 0, ws_f + 1, used);
    rqvae_finalize<<<1, NT, 0, stream>>>(ws_f, used, (float*)d_out);
}